// Round 6
// baseline (427.854 us; speedup 1.0000x reference)
//
#include <hip/hip_runtime.h>

#define BATCH 4
#define CIN 64
#define HH 352
#define WW 1216
#define OCH 8
#define OHH 354
#define OWW 1218
#define HW (HH * WW)

#define PX 4        // cols per thread
#define TY 2        // rows per thread
#define TILE_W 64   // 16 tx * 4
#define TILE_H 16   // 8 ty * 2
#define NTHR 128

// Repack weights with BN folded in: w2[c*72 + (dh*3+dw)*8 + oc] = conv_w[oc][c][dh][dw] * scl[oc]
// bias at w2[4608 + oc] = beta - mean*scl
__global__ void repack_kernel(const float* __restrict__ conv_w,
                              const float* __restrict__ gamma,
                              const float* __restrict__ beta,
                              const float* __restrict__ mean,
                              const float* __restrict__ var,
                              float* __restrict__ w2)
{
    int tid = blockIdx.x * 256 + threadIdx.x;
    if (tid < CIN * 9 * OCH) {
        int ct = tid >> 3;   // c*9 + tap
        int oc = tid & 7;
        float scl = gamma[oc] * rsqrtf(var[oc] + 1e-5f);
        w2[tid] = conv_w[oc * (CIN * 9) + ct] * scl;
    }
    if (tid < OCH) {
        float scl = gamma[tid] * rsqrtf(var[tid] + 1e-5f);
        w2[CIN * 9 * OCH + tid] = beta[tid] - mean[tid] * scl;
    }
}

// Zero only the uncovered border of each (b,t) plane (~5K px each) instead of 62 MB memset.
__global__ void border_kernel(float* __restrict__ out)
{
    const int bt = blockIdx.x;          // 0..35
    const int t = bt % 9;
    const int i = t / 3, j = t % 3;
    float* pl = out + (size_t)bt * OHH * OWW;
    // uncovered rows: the 2 rows not in [i, i+HH); cols: the 2 not in [j, j+WW)
    const int r0 = (i == 0) ? HH : 0;
    const int r1 = (i == 2) ? 1 : (OHH - 1);
    const int c0 = (j == 0) ? WW : 0;
    const int c1 = (j == 2) ? 1 : (OWW - 1);
    const int nrow = 2 * OWW;
    for (int idx = threadIdx.x; idx < 2 * OWW + 2 * OHH; idx += blockDim.x) {
        if (idx < nrow) {
            int r = (idx < OWW) ? r0 : r1;
            int c = (idx < OWW) ? idx : idx - OWW;
            pl[(size_t)r * OWW + c] = 0.f;
        } else {
            int k = idx - nrow;
            int c = (k < OHH) ? c0 : c1;
            int r = (k < OHH) ? k : k - OHH;
            pl[(size_t)r * OWW + c] = 0.f;
        }
    }
}

#define FMAS(oy, dh) \
    _Pragma("unroll") for (int dw = 0; dw < 3; ++dw) { \
        _Pragma("unroll") for (int o = 0; o < OCH; ++o) { \
            float wv = wc[(dh) * 3 * OCH + dw * OCH + o]; \
            _Pragma("unroll") for (int p = 0; p < PX; ++p) \
                acc[oy][p][o] = fmaf(fr[p + dw], wv, acc[oy][p][o]); } }

// Shuffles are hoisted OUT of the selects: __shfl_* is convergent (ds_bpermute)
// and must not sit inside a divergent ternary — an inactive source lane returns
// undefined data. Here they run at full exec; the ternaries become v_cndmask.
#define DO_ROW(r, ...) { \
    float4 mm = m[r]; float b_ = bv[r]; \
    mm.x *= rowm[r]; mm.y *= rowm[r]; mm.z *= rowm[r]; mm.w *= rowm[r]; \
    b_ *= brm[r]; \
    float up = __shfl_up(mm.w, 1); \
    float dn = __shfl_down(mm.x, 1); \
    float lv = isL ? b_ : up; \
    float rv = isR ? b_ : dn; \
    float fr[6] = {lv, mm.x, mm.y, mm.z, mm.w, rv}; \
    __VA_ARGS__ \
    if (c < CIN - 1) { \
        idxm[r] += HW; idxb[r] += HW; \
        m[r] = *(const float4*)(fp + idxm[r]); \
        bv[r] = fp[idxb[r]]; } }

__global__ __launch_bounds__(NTHR, 2)
void conv_kernel(const float* __restrict__ feature,
                 const float* __restrict__ w2all,
                 float* __restrict__ out)
{
    const int tid = threadIdx.x;
    const int tx = tid & 15, ty = tid >> 4;     // 16 x 8
    const int b  = blockIdx.z;
    const int h0 = blockIdx.y * TILE_H + ty * TY;
    const int w0 = blockIdx.x * TILE_W + tx * PX;

    const bool isL = (tx == 0);
    const bool isR = (tx == 15);
    const float lmv = (w0 >= 1) ? 1.f : 0.f;
    const float rmv = (w0 + 4 < WW) ? 1.f : 0.f;
    const float blrm = isL ? lmv : (isR ? rmv : 1.f);
    // boundary column this lane is responsible for (dummy = own col for middle lanes)
    const int bcol = isL ? max(w0 - 1, 0) : (isR ? min(w0 + 4, WW - 1) : w0);

    int idxm[4], idxb[4];
    float rowm[4], brm[4];
#pragma unroll
    for (int r = 0; r < 4; ++r) {
        int gh = h0 - 1 + r;
        bool rok = (unsigned)gh < (unsigned)HH;
        int sgh = min(max(gh, 0), HH - 1);
        idxm[r] = sgh * WW + w0;
        idxb[r] = sgh * WW + bcol;
        rowm[r] = rok ? 1.f : 0.f;
        brm[r]  = rowm[r] * blrm;
    }

    const float* fp = feature + (size_t)b * CIN * HW;

    // Prologue: fill ring with channel 0
    float4 m[4];
    float bv[4];
#pragma unroll
    for (int r = 0; r < 4; ++r) {
        m[r]  = *(const float4*)(fp + idxm[r]);
        bv[r] = fp[idxb[r]];
    }

    float acc[TY][PX][OCH];
#pragma unroll
    for (int oy = 0; oy < TY; ++oy)
#pragma unroll
        for (int p = 0; p < PX; ++p)
#pragma unroll
            for (int o = 0; o < OCH; ++o) acc[oy][p][o] = 0.f;

#pragma unroll 1
    for (int c = 0; c < CIN; ++c) {
        const float* wc = w2all + c * 72;   // uniform -> s_load
        DO_ROW(0, FMAS(0, 0))
        DO_ROW(1, FMAS(0, 1) FMAS(1, 0))
        DO_ROW(2, FMAS(0, 2) FMAS(1, 1))
        DO_ROW(3, FMAS(1, 2))
    }

    // Epilogue: bias, L1-normalize, mid, scatter 9 shifted planes.
    const float* bb = w2all + CIN * 9 * OCH;
    float sb[OCH];
#pragma unroll
    for (int o = 0; o < OCH; ++o) sb[o] = bb[o];

    float* ob = out + (size_t)b * 9 * OHH * OWW;
#pragma unroll
    for (int oy = 0; oy < TY; ++oy) {
        const int h = h0 + oy;
#pragma unroll
        for (int p = 0; p < PX; ++p) {
            const int w = w0 + p;
            float g[OCH];
            float asum = 0.f;
#pragma unroll
            for (int o = 0; o < OCH; ++o) {
                float v = acc[oy][p][o] + sb[o];
                g[o] = v;
                asum += fabsf(v);
            }
            float inv = 1.0f / asum;
            float ss = 0.f;
#pragma unroll
            for (int o = 0; o < OCH; ++o) { g[o] *= inv; ss += g[o]; }
            float mid = 1.0f - ss;
#pragma unroll
            for (int t = 0; t < 9; ++t) {
                int i = t / 3, j = t - i * 3;
                float v = (t < 4) ? g[t] : ((t == 4) ? mid : g[t - 1]);
                ob[((size_t)t * OHH + (h + i)) * OWW + (w + j)] = v;
            }
        }
    }
}

extern "C" void kernel_launch(void* const* d_in, const int* in_sizes, int n_in,
                              void* d_out, int out_size, void* d_ws, size_t ws_size,
                              hipStream_t stream) {
    const float* feature = (const float*)d_in[0];
    const float* conv_w  = (const float*)d_in[1];
    const float* gamma   = (const float*)d_in[2];
    const float* beta    = (const float*)d_in[3];
    const float* mean    = (const float*)d_in[4];
    const float* var     = (const float*)d_in[5];
    float* out = (float*)d_out;
    float* w2  = (float*)d_ws;   // 4608 + 8 floats

    border_kernel<<<BATCH * 9, 256, 0, stream>>>(out);
    repack_kernel<<<(CIN * 9 * OCH + 255) / 256, 256, 0, stream>>>(
        conv_w, gamma, beta, mean, var, w2);

    dim3 grid(WW / TILE_W, HH / TILE_H, BATCH);  // 19 x 22 x 4
    conv_kernel<<<grid, NTHR, 0, stream>>>(feature, w2, out);
}

// Round 7
// 264.945 us; speedup vs baseline: 1.6149x; 1.6149x over previous
//
#include <hip/hip_runtime.h>

#define BATCH 4
#define CIN 64
#define HH 352
#define WW 1216
#define OCH 8
#define OHH 354
#define OWW 1218
#define HW (HH * WW)

#define PX 4        // cols per thread
#define TY 2        // rows per thread
#define TILE_W 64   // 16 tx * 4
#define TILE_H 16   // 8 ty * 2
#define NTHR 128

// Repack weights with BN folded in: w2[c*72 + (dh*3+dw)*8 + oc] = conv_w[oc][c][dh][dw] * scl[oc]
// bias at w2[4608 + oc] = beta - mean*scl
__global__ void repack_kernel(const float* __restrict__ conv_w,
                              const float* __restrict__ gamma,
                              const float* __restrict__ beta,
                              const float* __restrict__ mean,
                              const float* __restrict__ var,
                              float* __restrict__ w2)
{
    int tid = blockIdx.x * 256 + threadIdx.x;
    if (tid < CIN * 9 * OCH) {
        int ct = tid >> 3;   // c*9 + tap
        int oc = tid & 7;
        float scl = gamma[oc] * rsqrtf(var[oc] + 1e-5f);
        w2[tid] = conv_w[oc * (CIN * 9) + ct] * scl;
    }
    if (tid < OCH) {
        float scl = gamma[tid] * rsqrtf(var[tid] + 1e-5f);
        w2[CIN * 9 * OCH + tid] = beta[tid] - mean[tid] * scl;
    }
}

// Zero only the uncovered border of each (b,t) plane (~5K px each) instead of 62 MB memset.
__global__ void border_kernel(float* __restrict__ out)
{
    const int bt = blockIdx.x;          // 0..35
    const int t = bt % 9;
    const int i = t / 3, j = t % 3;
    float* pl = out + (size_t)bt * OHH * OWW;
    const int r0 = (i == 0) ? HH : 0;
    const int r1 = (i == 2) ? 1 : (OHH - 1);
    const int c0 = (j == 0) ? WW : 0;
    const int c1 = (j == 2) ? 1 : (OWW - 1);
    const int nrow = 2 * OWW;
    for (int idx = threadIdx.x; idx < 2 * OWW + 2 * OHH; idx += blockDim.x) {
        if (idx < nrow) {
            int r = (idx < OWW) ? r0 : r1;
            int c = (idx < OWW) ? idx : idx - OWW;
            pl[(size_t)r * OWW + c] = 0.f;
        } else {
            int k = idx - nrow;
            int c = (k < OHH) ? c0 : c1;
            int r = (k < OHH) ? k : k - OHH;
            pl[(size_t)r * OWW + c] = 0.f;
        }
    }
}

// Issue one channel's 12 loads (per row: float4 center + 2 edge dwords), all independent.
#define LOADCH(PRE, cb) { \
    _Pragma("unroll") for (int r = 0; r < 4; ++r) { \
        PRE##m[r] = *(const float4*)((cb) + offc[r]); \
        PRE##l[r] = (cb)[offl[r]]; \
        PRE##r[r] = (cb)[offr[r]]; \
    } }

// Consume one buffered channel: build masked f[4][6], then 288 FMAs (no buffer reads).
#define CONSUME(PRE, CC) { \
    const float* wc = w2all + (CC) * 72; \
    float f[4][6]; \
    _Pragma("unroll") for (int r = 0; r < 4; ++r) { \
        f[r][0] = PRE##l[r] * rowm[r] * mvl; \
        f[r][1] = PRE##m[r].x * rowm[r]; \
        f[r][2] = PRE##m[r].y * rowm[r]; \
        f[r][3] = PRE##m[r].z * rowm[r]; \
        f[r][4] = PRE##m[r].w * rowm[r]; \
        f[r][5] = PRE##r[r] * rowm[r] * mvr; \
    } \
    _Pragma("unroll") for (int dh = 0; dh < 3; ++dh) \
    _Pragma("unroll") for (int dw = 0; dw < 3; ++dw) \
    _Pragma("unroll") for (int o = 0; o < OCH; ++o) { \
        float wv = wc[(dh * 3 + dw) * OCH + o]; \
        _Pragma("unroll") for (int oy = 0; oy < TY; ++oy) \
        _Pragma("unroll") for (int p = 0; p < PX; ++p) \
            acc[oy][p][o] = fmaf(f[oy + dh][p + dw], wv, acc[oy][p][o]); \
    } }

__global__ __launch_bounds__(NTHR, 2)
void conv_kernel(const float* __restrict__ feature,
                 const float* __restrict__ w2all,
                 float* __restrict__ out)
{
    const int tid = threadIdx.x;
    const int tx = tid & 15, ty = tid >> 4;     // 16 x 8
    const int b  = blockIdx.z;
    const int h0 = blockIdx.y * TILE_H + ty * TY;
    const int w0 = blockIdx.x * TILE_W + tx * PX;

    const int   cl  = max(w0 - 1, 0);
    const int   cr  = min(w0 + 4, WW - 1);
    const float mvl = (w0 >= 1) ? 1.f : 0.f;
    const float mvr = (w0 + 4 < WW) ? 1.f : 0.f;

    int offc[4], offl[4], offr[4];
    float rowm[4];
#pragma unroll
    for (int r = 0; r < 4; ++r) {
        int gh = h0 - 1 + r;
        bool rok = (unsigned)gh < (unsigned)HH;
        int sgh = min(max(gh, 0), HH - 1);
        offc[r] = sgh * WW + w0;
        offl[r] = sgh * WW + cl;
        offr[r] = sgh * WW + cr;
        rowm[r] = rok ? 1.f : 0.f;
    }

    const float* fp = feature + (size_t)b * CIN * HW;

    float4 a_m[4]; float a_l[4], a_r[4];
    float4 b_m[4]; float b_l[4], b_r[4];

    // Prologue: channel 0 into A
    LOADCH(a_, fp)

    float acc[TY][PX][OCH];
#pragma unroll
    for (int oy = 0; oy < TY; ++oy)
#pragma unroll
        for (int p = 0; p < PX; ++p)
#pragma unroll
            for (int o = 0; o < OCH; ++o) acc[oy][p][o] = 0.f;

#pragma unroll 1
    for (int c = 0; c < CIN; c += 2) {
        const float* cb1 = fp + (size_t)(c + 1) * HW;
        LOADCH(b_, cb1)          // prefetch c+1 while computing c
        CONSUME(a_, c)
        int c2 = (c + 2 < CIN) ? (c + 2) : (CIN - 1);   // clamped dead load on last iter
        const float* cb2 = fp + (size_t)c2 * HW;
        LOADCH(a_, cb2)          // prefetch c+2 while computing c+1
        CONSUME(b_, c + 1)
    }

    // Epilogue: bias, L1-normalize, mid, scatter 9 shifted planes.
    const float* bb = w2all + CIN * 9 * OCH;
    float sb[OCH];
#pragma unroll
    for (int o = 0; o < OCH; ++o) sb[o] = bb[o];

    float* ob = out + (size_t)b * 9 * OHH * OWW;
#pragma unroll
    for (int oy = 0; oy < TY; ++oy) {
        const int h = h0 + oy;
#pragma unroll
        for (int p = 0; p < PX; ++p) {
            const int w = w0 + p;
            float g[OCH];
            float asum = 0.f;
#pragma unroll
            for (int o = 0; o < OCH; ++o) {
                float v = acc[oy][p][o] + sb[o];
                g[o] = v;
                asum += fabsf(v);
            }
            float inv = 1.0f / asum;
            float ss = 0.f;
#pragma unroll
            for (int o = 0; o < OCH; ++o) { g[o] *= inv; ss += g[o]; }
            float mid = 1.0f - ss;
#pragma unroll
            for (int t = 0; t < 9; ++t) {
                int i = t / 3, j = t - i * 3;
                float v = (t < 4) ? g[t] : ((t == 4) ? mid : g[t - 1]);
                ob[((size_t)t * OHH + (h + i)) * OWW + (w + j)] = v;
            }
        }
    }
}

extern "C" void kernel_launch(void* const* d_in, const int* in_sizes, int n_in,
                              void* d_out, int out_size, void* d_ws, size_t ws_size,
                              hipStream_t stream) {
    const float* feature = (const float*)d_in[0];
    const float* conv_w  = (const float*)d_in[1];
    const float* gamma   = (const float*)d_in[2];
    const float* beta    = (const float*)d_in[3];
    const float* mean    = (const float*)d_in[4];
    const float* var     = (const float*)d_in[5];
    float* out = (float*)d_out;
    float* w2  = (float*)d_ws;   // 4608 + 8 floats

    border_kernel<<<BATCH * 9, 256, 0, stream>>>(out);
    repack_kernel<<<(CIN * 9 * OCH + 255) / 256, 256, 0, stream>>>(
        conv_w, gamma, beta, mean, var, w2);

    dim3 grid(WW / TILE_W, HH / TILE_H, BATCH);  // 19 x 22 x 4
    conv_kernel<<<grid, NTHR, 0, stream>>>(feature, w2, out);
}

// Round 8
// 260.390 us; speedup vs baseline: 1.6431x; 1.0175x over previous
//
#include <hip/hip_runtime.h>

#define BATCH 4
#define CIN 64
#define HH 352
#define WW 1216
#define OCH 8
#define OHH 354
#define OWW 1218
#define HW (HH * WW)

#define PX 4        // cols per thread
#define TY 2        // rows per thread
#define TILE_W 64   // 16 tx * 4
#define TILE_H 16   // 8 ty * 2
#define NTHR 128

typedef float v2f __attribute__((ext_vector_type(2)));

// Repack weights with BN folded in: w2[c*72 + (dh*3+dw)*8 + oc] = conv_w[oc][c][dh][dw] * scl[oc]
// bias at w2[4608 + oc] = beta - mean*scl
__global__ void repack_kernel(const float* __restrict__ conv_w,
                              const float* __restrict__ gamma,
                              const float* __restrict__ beta,
                              const float* __restrict__ mean,
                              const float* __restrict__ var,
                              float* __restrict__ w2)
{
    int tid = blockIdx.x * 256 + threadIdx.x;
    if (tid < CIN * 9 * OCH) {
        int ct = tid >> 3;   // c*9 + tap
        int oc = tid & 7;
        float scl = gamma[oc] * rsqrtf(var[oc] + 1e-5f);
        w2[tid] = conv_w[oc * (CIN * 9) + ct] * scl;
    }
    if (tid < OCH) {
        float scl = gamma[tid] * rsqrtf(var[tid] + 1e-5f);
        w2[CIN * 9 * OCH + tid] = beta[tid] - mean[tid] * scl;
    }
}

// Zero only the uncovered border of each (b,t) plane instead of 62 MB memset.
__global__ void border_kernel(float* __restrict__ out)
{
    const int bt = blockIdx.x;          // 0..35
    const int t = bt % 9;
    const int i = t / 3, j = t % 3;
    float* pl = out + (size_t)bt * OHH * OWW;
    const int r0 = (i == 0) ? HH : 0;
    const int r1 = (i == 2) ? 1 : (OHH - 1);
    const int c0 = (j == 0) ? WW : 0;
    const int c1 = (j == 2) ? 1 : (OWW - 1);
    const int nrow = 2 * OWW;
    for (int idx = threadIdx.x; idx < 2 * OWW + 2 * OHH; idx += blockDim.x) {
        if (idx < nrow) {
            int r = (idx < OWW) ? r0 : r1;
            int c = (idx < OWW) ? idx : idx - OWW;
            pl[(size_t)r * OWW + c] = 0.f;
        } else {
            int k = idx - nrow;
            int c = (k < OHH) ? c0 : c1;
            int r = (k < OHH) ? k : k - OHH;
            pl[(size_t)r * OWW + c] = 0.f;
        }
    }
}

// Issue one channel's 12 loads (per row: float4 center + 2 edge dwords), all independent.
#define LOADCH(PRE, cb) { \
    _Pragma("unroll") for (int r = 0; r < 4; ++r) { \
        PRE##m[r] = *(const float4*)((cb) + offc[r]); \
        PRE##l[r] = (cb)[offl[r]]; \
        PRE##r[r] = (cb)[offr[r]]; \
    } }

// Consume one buffered channel using packed float2 FMAs (v_pk_fma_f32).
// Row r taps: f[0]=e0 f[1..4]=center f[5]=e5. Pair views:
//   q01=(f0,f1) c12=(f1,f2) q23=(f2,f3) c34=(f3,f4) q45=(f4,f5)
// dw=0 -> (q01,q23); dw=1 -> (c12,c34); dw=2 -> (q23,q45)
#define CONSUME(PRE, CC) { \
    const float* wc = w2all + (CC) * 72; \
    v2f c12[4], c34[4], q01[4], q23[4], q45[4]; \
    _Pragma("unroll") for (int r = 0; r < 4; ++r) { \
        float e0 = PRE##l[r] * mls[r]; \
        float e5 = PRE##r[r] * mrs[r]; \
        v2f rm2; rm2.x = rowm[r]; rm2.y = rowm[r]; \
        v2f t12; t12.x = PRE##m[r].x; t12.y = PRE##m[r].y; \
        v2f t34; t34.x = PRE##m[r].z; t34.y = PRE##m[r].w; \
        c12[r] = t12 * rm2; \
        c34[r] = t34 * rm2; \
        q01[r].x = e0;        q01[r].y = c12[r].x; \
        q23[r].x = c12[r].y;  q23[r].y = c34[r].x; \
        q45[r].x = c34[r].y;  q45[r].y = e5; \
    } \
    _Pragma("unroll") for (int dh = 0; dh < 3; ++dh) \
    _Pragma("unroll") for (int o = 0; o < OCH; ++o) { \
        float w0 = wc[(dh * 3 + 0) * OCH + o]; \
        float w1 = wc[(dh * 3 + 1) * OCH + o]; \
        float w2v = wc[(dh * 3 + 2) * OCH + o]; \
        v2f W0; W0.x = w0; W0.y = w0; \
        v2f W1; W1.x = w1; W1.y = w1; \
        v2f W2; W2.x = w2v; W2.y = w2v; \
        _Pragma("unroll") for (int oy = 0; oy < TY; ++oy) { \
            const int ry = oy + dh; \
            acc2[oy][0][o] = __builtin_elementwise_fma(q01[ry], W0, \
                             __builtin_elementwise_fma(c12[ry], W1, \
                             __builtin_elementwise_fma(q23[ry], W2, acc2[oy][0][o]))); \
            acc2[oy][1][o] = __builtin_elementwise_fma(q23[ry], W0, \
                             __builtin_elementwise_fma(c34[ry], W1, \
                             __builtin_elementwise_fma(q45[ry], W2, acc2[oy][1][o]))); \
        } \
    } }

__global__ __launch_bounds__(NTHR, 2)
void conv_kernel(const float* __restrict__ feature,
                 const float* __restrict__ w2all,
                 float* __restrict__ out)
{
    const int tid = threadIdx.x;
    const int tx = tid & 15, ty = tid >> 4;     // 16 x 8
    const int b  = blockIdx.z;
    const int h0 = blockIdx.y * TILE_H + ty * TY;
    const int w0 = blockIdx.x * TILE_W + tx * PX;

    const int   cl  = max(w0 - 1, 0);
    const int   cr  = min(w0 + 4, WW - 1);
    const float mvl = (w0 >= 1) ? 1.f : 0.f;
    const float mvr = (w0 + 4 < WW) ? 1.f : 0.f;

    int offc[4], offl[4], offr[4];
    float rowm[4], mls[4], mrs[4];
#pragma unroll
    for (int r = 0; r < 4; ++r) {
        int gh = h0 - 1 + r;
        bool rok = (unsigned)gh < (unsigned)HH;
        int sgh = min(max(gh, 0), HH - 1);
        offc[r] = sgh * WW + w0;
        offl[r] = sgh * WW + cl;
        offr[r] = sgh * WW + cr;
        rowm[r] = rok ? 1.f : 0.f;
        mls[r]  = rowm[r] * mvl;
        mrs[r]  = rowm[r] * mvr;
    }

    const float* fp = feature + (size_t)b * CIN * HW;

    float4 a_m[4]; float a_l[4], a_r[4];
    float4 b_m[4]; float b_l[4], b_r[4];

    // Prologue: channel 0 into A
    LOADCH(a_, fp)

    v2f acc2[TY][2][OCH];
#pragma unroll
    for (int oy = 0; oy < TY; ++oy)
#pragma unroll
        for (int xp = 0; xp < 2; ++xp)
#pragma unroll
            for (int o = 0; o < OCH; ++o) { acc2[oy][xp][o].x = 0.f; acc2[oy][xp][o].y = 0.f; }

#pragma unroll 1
    for (int c = 0; c < CIN; c += 2) {
        const float* cb1 = fp + (size_t)(c + 1) * HW;
        LOADCH(b_, cb1)          // prefetch c+1 while computing c
        CONSUME(a_, c)
        int c2 = (c + 2 < CIN) ? (c + 2) : (CIN - 1);   // clamped dead load on last iter
        const float* cb2 = fp + (size_t)c2 * HW;
        LOADCH(a_, cb2)          // prefetch c+2 while computing c+1
        CONSUME(b_, c + 1)
    }

    // Epilogue: bias, L1-normalize, mid, scatter 9 shifted planes.
    const float* bb = w2all + CIN * 9 * OCH;
    float sb[OCH];
#pragma unroll
    for (int o = 0; o < OCH; ++o) sb[o] = bb[o];

    float* ob = out + (size_t)b * 9 * OHH * OWW;
#pragma unroll
    for (int oy = 0; oy < TY; ++oy) {
        const int h = h0 + oy;
#pragma unroll
        for (int p = 0; p < PX; ++p) {
            const int w = w0 + p;
            float g[OCH];
            float asum = 0.f;
#pragma unroll
            for (int o = 0; o < OCH; ++o) {
                float av = (p < 2) ? ((p & 1) ? acc2[oy][0][o].y : acc2[oy][0][o].x)
                                   : ((p & 1) ? acc2[oy][1][o].y : acc2[oy][1][o].x);
                float v = av + sb[o];
                g[o] = v;
                asum += fabsf(v);
            }
            float inv = 1.0f / asum;
            float ss = 0.f;
#pragma unroll
            for (int o = 0; o < OCH; ++o) { g[o] *= inv; ss += g[o]; }
            float mid = 1.0f - ss;
#pragma unroll
            for (int t = 0; t < 9; ++t) {
                int i = t / 3, j = t - i * 3;
                float v = (t < 4) ? g[t] : ((t == 4) ? mid : g[t - 1]);
                ob[((size_t)t * OHH + (h + i)) * OWW + (w + j)] = v;
            }
        }
    }
}

extern "C" void kernel_launch(void* const* d_in, const int* in_sizes, int n_in,
                              void* d_out, int out_size, void* d_ws, size_t ws_size,
                              hipStream_t stream) {
    const float* feature = (const float*)d_in[0];
    const float* conv_w  = (const float*)d_in[1];
    const float* gamma   = (const float*)d_in[2];
    const float* beta    = (const float*)d_in[3];
    const float* mean    = (const float*)d_in[4];
    const float* var     = (const float*)d_in[5];
    float* out = (float*)d_out;
    float* w2  = (float*)d_ws;   // 4608 + 8 floats

    border_kernel<<<BATCH * 9, 256, 0, stream>>>(out);
    repack_kernel<<<(CIN * 9 * OCH + 255) / 256, 256, 0, stream>>>(
        conv_w, gamma, beta, mean, var, w2);

    dim3 grid(WW / TILE_W, HH / TILE_H, BATCH);  // 19 x 22 x 4
    conv_kernel<<<grid, NTHR, 0, stream>>>(feature, w2, out);
}